// Round 1
// 463.770 us; speedup vs baseline: 1.0292x; 1.0292x over previous
//
#include <hip/hip_runtime.h>

typedef unsigned short u16;
typedef unsigned int   u32;
typedef __bf16 bf16x8 __attribute__((ext_vector_type(8)));
typedef u16    u16x8  __attribute__((ext_vector_type(8)));
typedef float  f32x4  __attribute__((ext_vector_type(4)));

#define DI static __device__ __forceinline__

DI float b2f(u16 u){ union { u32 i; float f; } c; c.i = ((u32)u) << 16; return c.f; }
DI u16 f2b(float f){ union { float f; u32 i; } c; c.f = f; u32 i = c.i;
                     return (u16)((i + 0x7FFFu + ((i >> 16) & 1u)) >> 16); }
DI float eluf(float x){ return x > 0.f ? x : (__expf(x) - 1.f); }
DI float sigf(float x){ return 1.f / (1.f + __expf(-x)); }
DI f32x4 mfma16(bf16x8 a, bf16x8 b, f32x4 c){
  return __builtin_amdgcn_mfma_f32_16x16x32_bf16(a, b, c, 0, 0, 0);
}
DI bf16x8 ldb(const u16* p){ return *(const bf16x8*)p; }

// ---------------------------------------------------------------------------
// Pack x (fp32 -> bf16 A-fragment layout) and all weights (fp32 -> bf16
// B-fragment layout).
//   pX[rowblk 1024][kcg 32][lane 64][8]: elem = x[rowblk*16 + (lane&15)]
//                                             [kcg*32 + (lane>>4)*8 + j]
//   weight frags: elem = W[k = kc*32 + (lane>>4)*8 + j][n = nb*16 + (lane&15)]
// Ranges (8-elem groups): pX 2097152 | pW1 34816 | pF1 32768 | pSk 32768 |
//                         pF2 131072 | pGa 131072   (total 2459648)
// ---------------------------------------------------------------------------
__global__ __launch_bounds__(256) void k_pack(
    const float* __restrict__ x,
    const float* __restrict__ wfc1, const float* __restrict__ wskip,
    const float* __restrict__ vfc1, const float* __restrict__ vfc2,
    const float* __restrict__ vgate, const float* __restrict__ vskip,
    u16* __restrict__ pX, u16* __restrict__ pW1, u16* __restrict__ pF1,
    u16* __restrict__ pSk, u16* __restrict__ pF2, u16* __restrict__ pGa)
{
  const int g = blockIdx.x * 256 + threadIdx.x;   // 2459648 total
  float v8[8];
  u16* dst;
  if (g < 2097152){               // pX
    int idx = g, lane = idx & 63, kc = (idx >> 6) & 31, rb = idx >> 11;
    int ln = lane & 15, q = lane >> 4;
    const float* xp = &x[(size_t)(rb * 16 + ln) * 1024 + kc * 32 + q * 8];
    float4 lo = *(const float4*)xp, hi = *(const float4*)(xp + 4);
    v8[0]=lo.x; v8[1]=lo.y; v8[2]=lo.z; v8[3]=lo.w;
    v8[4]=hi.x; v8[5]=hi.y; v8[6]=hi.z; v8[7]=hi.w;
    dst = pX + (size_t)idx * 8;
  } else {
    int h = g - 2097152;
    if (h < 34816){               // pW1: nb 0..16, kc 0..31 (K=1024)
      int idx = h, lane = idx & 63, kc = (idx >> 6) & 31, nb = idx >> 11;
      int ln = lane & 15, q = lane >> 4;
      #pragma unroll
      for (int j = 0; j < 8; j++){
        int k = kc * 32 + q * 8 + j;
        v8[j] = (nb < 16) ? wfc1[(size_t)k * 256 + nb * 16 + ln]
                          : wskip[(size_t)k * 16 + ln];
      }
      dst = pW1 + (size_t)idx * 8;
    } else if (h < 67584){        // pF1: v, nb 0..15, kc 0..1 (K=64)
      int idx = h - 34816, lane = idx & 63, kc = (idx >> 6) & 1, nb = (idx >> 7) & 15, v = idx >> 11;
      int ln = lane & 15, q = lane >> 4;
      #pragma unroll
      for (int j = 0; j < 8; j++){
        int k = kc * 32 + q * 8 + j;
        v8[j] = vfc1[((size_t)v * 64 + k) * 256 + nb * 16 + ln];
      }
      dst = pF1 + (size_t)idx * 8;
    } else if (h < 100352){       // pSk
      int idx = h - 67584, lane = idx & 63, kc = (idx >> 6) & 1, nb = (idx >> 7) & 15, v = idx >> 11;
      int ln = lane & 15, q = lane >> 4;
      #pragma unroll
      for (int j = 0; j < 8; j++){
        int k = kc * 32 + q * 8 + j;
        v8[j] = vskip[((size_t)v * 64 + k) * 256 + nb * 16 + ln];
      }
      dst = pSk + (size_t)idx * 8;
    } else if (h < 231424){       // pF2: v, nb, kc 0..7 (K=256)
      int idx = h - 100352, lane = idx & 63, kc = (idx >> 6) & 7, nb = (idx >> 9) & 15, v = idx >> 13;
      int ln = lane & 15, q = lane >> 4;
      #pragma unroll
      for (int j = 0; j < 8; j++){
        int k = kc * 32 + q * 8 + j;
        v8[j] = vfc2[((size_t)v * 256 + k) * 256 + nb * 16 + ln];
      }
      dst = pF2 + (size_t)idx * 8;
    } else {                      // pGa
      int idx = h - 231424, lane = idx & 63, kc = (idx >> 6) & 7, nb = (idx >> 9) & 15, v = idx >> 13;
      int ln = lane & 15, q = lane >> 4;
      #pragma unroll
      for (int j = 0; j < 8; j++){
        int k = kc * 32 + q * 8 + j;
        v8[j] = vgate[((size_t)v * 256 + k) * 256 + nb * 16 + ln];
      }
      dst = pGa + (size_t)idx * 8;
    }
  }
  u16x8 t;
  #pragma unroll
  for (int j = 0; j < 8; j++) t[j] = f2b(v8[j]);
  *(uint4*)dst = __builtin_bit_cast(uint4, t);
}

// ---------------------------------------------------------------------------
// Kernel 1: weight GRN -> softmax weights w [N,16] (fp32, in ws).
// 512 blocks x 32 rows (2 blocks/CU), 512 threads = 8 waves.
// Waves 0..6 -> nb {2w,2w+1}; wave 7 -> nb {14,15,16(=skip)}. A-frags from
// pre-packed pX (no cvt). Also zeroes its 32 rows of `out` for k_var_grn's
// atomicAdd accumulation. h kept fp32 in LDS (only consumer is the scalar
// y-epilogue).
// ---------------------------------------------------------------------------
__global__ __launch_bounds__(512, 4) void k_weight_grn(
    const u16* __restrict__ pX, const u16* __restrict__ pW1,
    const float* __restrict__ b1, const float* __restrict__ W2, const float* __restrict__ b2,
    const float* __restrict__ Wg, const float* __restrict__ bg, const float* __restrict__ bs,
    float* __restrict__ w_out, float* __restrict__ out_zero)
{
  __shared__ float sHf[32 * 264];    // fp32 h
  __shared__ float sR[32 * 16];      // res fp32
  __shared__ float sY[32 * 16];
  __shared__ float sG[32 * 16];
  __shared__ float sW2f[256 * 16];   // fp32 W2
  __shared__ float sWgf[256];        // fp32 Wg

  const int tid  = threadIdx.x;
  const int lane = tid & 63;
  const int wid  = tid >> 6;
  const int ln   = lane & 15;
  const int q    = lane >> 4;
  const int row0 = blockIdx.x * 32;
  const int nb0  = wid * 2;
  const int ncnt = (wid == 7) ? 3 : 2;

  // zero the out region this block's rows map to (consumed by k_var_grn atomics)
  {
    float4 zz; zz.x = 0.f; zz.y = 0.f; zz.z = 0.f; zz.w = 0.f;
    #pragma unroll
    for (int u = 0; u < 4; u++)
      *(float4*)&out_zero[(size_t)row0 * 256 + tid * 16 + u * 4] = zz;
  }
  // stage W2 [256][16] fp32 + Wg (before MFMA loop so loads overlap)
  #pragma unroll
  for (int u = 0; u < 2; u++)
    *(float4*)&sW2f[tid * 8 + u * 4] = *(const float4*)&W2[tid * 8 + u * 4];
  if (tid < 256) sWgf[tid] = Wg[tid];

  f32x4 acc[2][3];
  #pragma unroll
  for (int mb = 0; mb < 2; mb++)
    #pragma unroll
    for (int i = 0; i < 3; i++){ acc[mb][i][0]=0.f; acc[mb][i][1]=0.f; acc[mb][i][2]=0.f; acc[mb][i][3]=0.f; }

  for (int kc = 0; kc < 32; kc++){
    bf16x8 a[2];
    #pragma unroll
    for (int mb = 0; mb < 2; mb++)
      a[mb] = ldb(&pX[((size_t)(blockIdx.x * 2 + mb) * 32 + kc) * 512 + lane * 8]);
    #pragma unroll
    for (int i = 0; i < 3; i++){
      if (i < ncnt){
        bf16x8 b = ldb(&pW1[(size_t)((nb0 + i) * 32 + kc) * 512 + lane * 8]);
        #pragma unroll
        for (int mb = 0; mb < 2; mb++) acc[mb][i] = mfma16(a[mb], b, acc[mb][i]);
      }
    }
  }

  // write h (fp32) / res (fp32)
  #pragma unroll
  for (int i = 0; i < 3; i++){
    if (i < ncnt){
      int nb = nb0 + i;
      int col = nb * 16 + ln;
      float vb = (nb < 16) ? b1[col] : bs[ln];
      #pragma unroll
      for (int mb = 0; mb < 2; mb++){
        #pragma unroll
        for (int r = 0; r < 4; r++){
          int lr = mb * 16 + q * 4 + r;
          float v = acc[mb][i][r] + vb;
          if (nb < 16) sHf[lr * 264 + col] = eluf(v);
          else         sR[lr * 16 + ln] = v;
        }
      }
    }
  }
  __syncthreads();

  // y = h @ W2 + b2 : thread r = tid>>4 (0..31), 1 col
  {
    int r = tid >> 4, j = tid & 15;
    float a0 = b2[j];
    #pragma unroll 8
    for (int k = 0; k < 256; k++)
      a0 += sHf[r * 264 + k] * sW2f[k * 16 + j];
    sY[r * 16 + j] = a0;
  }
  __syncthreads();

  // gate = sigmoid(y @ Wg + bg)
  {
    int r = tid >> 4, j = tid & 15;
    float g0 = bg[j];
    #pragma unroll
    for (int k = 0; k < 16; k++)
      g0 += sY[r * 16 + k] * sWgf[k * 16 + j];
    sG[r * 16 + j] = sigf(g0);
  }
  __syncthreads();

  // softmax over 16
  if (tid < 32){
    int r = tid;
    float l[16]; float m = -1e30f;
    #pragma unroll
    for (int j = 0; j < 16; j++){
      float v = sR[r * 16 + j] + sG[r * 16 + j] * sY[r * 16 + j];
      l[j] = v; m = fmaxf(m, v);
    }
    float s = 0.f;
    #pragma unroll
    for (int j = 0; j < 16; j++){ l[j] = __expf(l[j] - m); s += l[j]; }
    float inv = 1.f / s;
    #pragma unroll
    for (int j = 0; j < 16; j++) w_out[(size_t)(row0 + r) * 16 + j] = l[j] * inv;
  }
}

// ---------------------------------------------------------------------------
// Kernel 2: per-variable GRNs. 512 blocks (2/CU): blockIdx>>1 = 64-row group,
// blockIdx&1 = v-half (8 v's). bid&1 is constant per XCD under round-robin
// dispatch -> each XCD's L2 holds one 2.5 MB weight half. 512 threads =
// 8 waves; wave wid owns 32-col slice (nb {2w,2w+1}) for all 64 rows.
// A-frags direct from pre-packed pX (no cvt). Partial z accumulated into
// out via atomicAdd (out pre-zeroed by k_weight_grn; exactly 2 commutative
// adds per element -> deterministic).
// ---------------------------------------------------------------------------
__global__ __launch_bounds__(512, 4) void k_var_grn(
    const u16* __restrict__ pX,
    const u16* __restrict__ pF1, const u16* __restrict__ pSk,
    const u16* __restrict__ pF2, const u16* __restrict__ pGa,
    const float* __restrict__ b1, const float* __restrict__ b2,
    const float* __restrict__ bg, const float* __restrict__ bs,
    const float* __restrict__ w_in, float* __restrict__ out)
{
  __shared__ u16 sH[64 * 264];       // bf16 hv then yv
  __shared__ float sWt[64 * 16];     // softmax weights fp32

  const int tid  = threadIdx.x;
  const int lane = tid & 63;
  const int wid  = tid >> 6;
  const int ln   = lane & 15;
  const int q    = lane >> 4;
  const int row0 = (blockIdx.x >> 1) * 64;
  const int v0   = (blockIdx.x & 1) * 8;
  const int rb0  = row0 >> 4;
  const int nb0  = wid * 2;

  sWt[tid]       = w_in[(size_t)row0 * 16 + tid];
  sWt[tid + 512] = w_in[(size_t)row0 * 16 + 512 + tid];
  __syncthreads();

  f32x4 z[4][2];
  #pragma unroll
  for (int mb = 0; mb < 4; mb++)
    #pragma unroll
    for (int i = 0; i < 2; i++){ z[mb][i][0]=0.f; z[mb][i][1]=0.f; z[mb][i][2]=0.f; z[mb][i][3]=0.f; }

  #pragma unroll 1
  for (int vi = 0; vi < 8; vi++){
    const int v = v0 + vi;
    // A-fragments from pre-packed pX, kcg = v*2 + ks
    bf16x8 a0[4], a1[4];
    #pragma unroll
    for (int mb = 0; mb < 4; mb++){
      const u16* xp = &pX[((size_t)(rb0 + mb) * 32 + v * 2) * 512 + lane * 8];
      a0[mb] = ldb(xp);
      a1[mb] = ldb(xp + 512);
    }
    float wv[4][4];
    #pragma unroll
    for (int mb = 0; mb < 4; mb++)
      #pragma unroll
      for (int r = 0; r < 4; r++) wv[mb][r] = sWt[(mb * 16 + q * 4 + r) * 16 + v];

    // ---- phase 1a: hv = elu(Xv @ W1v + b1)
    f32x4 hacc[4][2];
    #pragma unroll
    for (int mb = 0; mb < 4; mb++)
      #pragma unroll
      for (int i = 0; i < 2; i++){ hacc[mb][i][0]=0.f; hacc[mb][i][1]=0.f; hacc[mb][i][2]=0.f; hacc[mb][i][3]=0.f; }
    #pragma unroll
    for (int ks = 0; ks < 2; ks++){
      bf16x8 B0 = ldb(&pF1[(size_t)((v * 16 + nb0) * 2 + ks) * 512 + lane * 8]);
      bf16x8 B1 = ldb(&pF1[(size_t)((v * 16 + nb0 + 1) * 2 + ks) * 512 + lane * 8]);
      #pragma unroll
      for (int mb = 0; mb < 4; mb++){
        bf16x8 a = ks ? a1[mb] : a0[mb];
        hacc[mb][0] = mfma16(a, B0, hacc[mb][0]);
        hacc[mb][1] = mfma16(a, B1, hacc[mb][1]);
      }
    }
    #pragma unroll
    for (int i = 0; i < 2; i++){
      int col = (nb0 + i) * 16 + ln;
      float vb = b1[v * 256 + col];
      #pragma unroll
      for (int mb = 0; mb < 4; mb++)
        #pragma unroll
        for (int r = 0; r < 4; r++)
          sH[(mb * 16 + q * 4 + r) * 264 + col] = f2b(eluf(hacc[mb][i][r] + vb));
    }

    // ---- phase 1b: rv = Xv @ Wsv + bs ; z += wv * rv  (no sH dependency)
    f32x4 racc[4][2];
    #pragma unroll
    for (int mb = 0; mb < 4; mb++)
      #pragma unroll
      for (int i = 0; i < 2; i++){ racc[mb][i][0]=0.f; racc[mb][i][1]=0.f; racc[mb][i][2]=0.f; racc[mb][i][3]=0.f; }
    #pragma unroll
    for (int ks = 0; ks < 2; ks++){
      bf16x8 B0 = ldb(&pSk[(size_t)((v * 16 + nb0) * 2 + ks) * 512 + lane * 8]);
      bf16x8 B1 = ldb(&pSk[(size_t)((v * 16 + nb0 + 1) * 2 + ks) * 512 + lane * 8]);
      #pragma unroll
      for (int mb = 0; mb < 4; mb++){
        bf16x8 a = ks ? a1[mb] : a0[mb];
        racc[mb][0] = mfma16(a, B0, racc[mb][0]);
        racc[mb][1] = mfma16(a, B1, racc[mb][1]);
      }
    }
    #pragma unroll
    for (int i = 0; i < 2; i++){
      float vb = bs[v * 256 + (nb0 + i) * 16 + ln];
      #pragma unroll
      for (int mb = 0; mb < 4; mb++)
        #pragma unroll
        for (int r = 0; r < 4; r++) z[mb][i][r] += wv[mb][r] * (racc[mb][i][r] + vb);
    }
    __syncthreads();   // (1) hv visible to all waves

    // ---- phase 2: yv = hv @ W2v + b2  (K=256 streamed, no inner barriers)
    f32x4 yacc[4][2];
    #pragma unroll
    for (int mb = 0; mb < 4; mb++)
      #pragma unroll
      for (int i = 0; i < 2; i++){ yacc[mb][i][0]=0.f; yacc[mb][i][1]=0.f; yacc[mb][i][2]=0.f; yacc[mb][i][3]=0.f; }
    #pragma unroll
    for (int kc = 0; kc < 8; kc++){
      bf16x8 B0 = ldb(&pF2[(size_t)((v * 16 + nb0) * 8 + kc) * 512 + lane * 8]);
      bf16x8 B1 = ldb(&pF2[(size_t)((v * 16 + nb0 + 1) * 8 + kc) * 512 + lane * 8]);
      #pragma unroll
      for (int mb = 0; mb < 4; mb++){
        bf16x8 ah = *(const bf16x8*)&sH[(mb * 16 + ln) * 264 + kc * 32 + q * 8];
        yacc[mb][0] = mfma16(ah, B0, yacc[mb][0]);
        yacc[mb][1] = mfma16(ah, B1, yacc[mb][1]);
      }
    }
    __syncthreads();   // (2) all hv reads done before yv overwrite

    f32x4 ysave[4][2];
    #pragma unroll
    for (int i = 0; i < 2; i++){
      int col = (nb0 + i) * 16 + ln;
      float vb = b2[v * 256 + col];
      #pragma unroll
      for (int mb = 0; mb < 4; mb++)
        #pragma unroll
        for (int r = 0; r < 4; r++){
          float yy = yacc[mb][i][r] + vb;
          ysave[mb][i][r] = yy;
          sH[(mb * 16 + q * 4 + r) * 264 + col] = f2b(yy);
        }
    }
    __syncthreads();   // (3) yv visible

    // ---- phase 3: gv = sigmoid(yv @ Wgv + bg)
    f32x4 gacc[4][2];
    #pragma unroll
    for (int mb = 0; mb < 4; mb++)
      #pragma unroll
      for (int i = 0; i < 2; i++){ gacc[mb][i][0]=0.f; gacc[mb][i][1]=0.f; gacc[mb][i][2]=0.f; gacc[mb][i][3]=0.f; }
    #pragma unroll
    for (int kc = 0; kc < 8; kc++){
      bf16x8 B0 = ldb(&pGa[(size_t)((v * 16 + nb0) * 8 + kc) * 512 + lane * 8]);
      bf16x8 B1 = ldb(&pGa[(size_t)((v * 16 + nb0 + 1) * 8 + kc) * 512 + lane * 8]);
      #pragma unroll
      for (int mb = 0; mb < 4; mb++){
        bf16x8 ah = *(const bf16x8*)&sH[(mb * 16 + ln) * 264 + kc * 32 + q * 8];
        gacc[mb][0] = mfma16(ah, B0, gacc[mb][0]);
        gacc[mb][1] = mfma16(ah, B1, gacc[mb][1]);
      }
    }
    #pragma unroll
    for (int i = 0; i < 2; i++){
      float vb = bg[v * 256 + (nb0 + i) * 16 + ln];
      #pragma unroll
      for (int mb = 0; mb < 4; mb++)
        #pragma unroll
        for (int r = 0; r < 4; r++)
          z[mb][i][r] += wv[mb][r] * sigf(gacc[mb][i][r] + vb) * ysave[mb][i][r];
    }
    __syncthreads();   // (4) yv reads done before next v's hv writes
  }

  // accumulate partial z -> out (fp32 atomics; out pre-zeroed)
  #pragma unroll
  for (int i = 0; i < 2; i++){
    int col = (nb0 + i) * 16 + ln;
    #pragma unroll
    for (int mb = 0; mb < 4; mb++)
      #pragma unroll
      for (int r = 0; r < 4; r++)
        atomicAdd(&out[(size_t)(row0 + mb * 16 + q * 4 + r) * 256 + col], z[mb][i][r]);
  }
}

// ---------------------------------------------------------------------------
extern "C" void kernel_launch(void* const* d_in, const int* in_sizes, int n_in,
                              void* d_out, int out_size, void* d_ws, size_t ws_size,
                              hipStream_t stream)
{
  const float* x     = (const float*)d_in[0];
  const float* wfc1w = (const float*)d_in[1];
  const float* wfc1b = (const float*)d_in[2];
  const float* wfc2w = (const float*)d_in[3];
  const float* wfc2b = (const float*)d_in[4];
  const float* wgw   = (const float*)d_in[5];
  const float* wgb   = (const float*)d_in[6];
  const float* wsw   = (const float*)d_in[7];
  const float* wsb   = (const float*)d_in[8];
  const float* vfc1w = (const float*)d_in[9];
  const float* vfc1b = (const float*)d_in[10];
  const float* vfc2w = (const float*)d_in[11];
  const float* vfc2b = (const float*)d_in[12];
  const float* vgw   = (const float*)d_in[13];
  const float* vgb   = (const float*)d_in[14];
  const float* vsw   = (const float*)d_in[15];
  const float* vsb   = (const float*)d_in[16];

  u16* ws   = (u16*)d_ws;
  u16* pX   = ws;                      // 16777216 u16 (32 MB)
  u16* pW1  = pX + 16777216;           // 278528 u16
  u16* pF1  = pW1 + 278528;            // 262144
  u16* pSk  = pF1 + 262144;            // 262144
  u16* pF2  = pSk + 262144;            // 1048576
  u16* pGa  = pF2 + 1048576;           // 1048576
  float* w_ws = (float*)(pGa + 1048576); // 16384*16 fp32

  k_pack<<<dim3(9608), dim3(256), 0, stream>>>(
      x, wfc1w, wsw, vfc1w, vfc2w, vgw, vsw, pX, pW1, pF1, pSk, pF2, pGa);

  k_weight_grn<<<dim3(512), dim3(512), 0, stream>>>(
      pX, pW1, wfc1b, wfc2w, wfc2b, wgw, wgb, wsb, w_ws, (float*)d_out);

  k_var_grn<<<dim3(512), dim3(512), 0, stream>>>(
      pX, pF1, pSk, pF2, pGa, vfc1b, vfc2b, vgb, vsb, w_ws, (float*)d_out);
}

// Round 2
// 353.455 us; speedup vs baseline: 1.3504x; 1.3121x over previous
//
#include <hip/hip_runtime.h>

typedef unsigned short u16;
typedef unsigned int   u32;
typedef __bf16 bf16x8 __attribute__((ext_vector_type(8)));
typedef u16    u16x8  __attribute__((ext_vector_type(8)));
typedef float  f32x4  __attribute__((ext_vector_type(4)));

#define DI static __device__ __forceinline__

DI float b2f(u16 u){ union { u32 i; float f; } c; c.i = ((u32)u) << 16; return c.f; }
DI u16 f2b(float f){ union { float f; u32 i; } c; c.f = f; u32 i = c.i;
                     return (u16)((i + 0x7FFFu + ((i >> 16) & 1u)) >> 16); }
DI float eluf(float x){ return x > 0.f ? x : (__expf(x) - 1.f); }
DI float sigf(float x){ return 1.f / (1.f + __expf(-x)); }
DI f32x4 mfma16(bf16x8 a, bf16x8 b, f32x4 c){
  return __builtin_amdgcn_mfma_f32_16x16x32_bf16(a, b, c, 0, 0, 0);
}
DI bf16x8 ldb(const u16* p){ return *(const bf16x8*)p; }

// ---------------------------------------------------------------------------
// Pack x (fp32 -> bf16 A-fragment layout) and all weights (fp32 -> bf16
// B-fragment layout).
//   pX[rowblk 1024][kcg 32][lane 64][8]: elem = x[rowblk*16 + (lane&15)]
//                                             [kcg*32 + (lane>>4)*8 + j]
//   weight frags: elem = W[k = kc*32 + (lane>>4)*8 + j][n = nb*16 + (lane&15)]
// Ranges (8-elem groups): pX 2097152 | pW1 34816 | pF1 32768 | pSk 32768 |
//                         pF2 131072 | pGa 131072   (total 2459648)
// ---------------------------------------------------------------------------
__global__ __launch_bounds__(256) void k_pack(
    const float* __restrict__ x,
    const float* __restrict__ wfc1, const float* __restrict__ wskip,
    const float* __restrict__ vfc1, const float* __restrict__ vfc2,
    const float* __restrict__ vgate, const float* __restrict__ vskip,
    u16* __restrict__ pX, u16* __restrict__ pW1, u16* __restrict__ pF1,
    u16* __restrict__ pSk, u16* __restrict__ pF2, u16* __restrict__ pGa)
{
  const int g = blockIdx.x * 256 + threadIdx.x;   // 2459648 total
  float v8[8];
  u16* dst;
  if (g < 2097152){               // pX
    int idx = g, lane = idx & 63, kc = (idx >> 6) & 31, rb = idx >> 11;
    int ln = lane & 15, q = lane >> 4;
    const float* xp = &x[(size_t)(rb * 16 + ln) * 1024 + kc * 32 + q * 8];
    float4 lo = *(const float4*)xp, hi = *(const float4*)(xp + 4);
    v8[0]=lo.x; v8[1]=lo.y; v8[2]=lo.z; v8[3]=lo.w;
    v8[4]=hi.x; v8[5]=hi.y; v8[6]=hi.z; v8[7]=hi.w;
    dst = pX + (size_t)idx * 8;
  } else {
    int h = g - 2097152;
    if (h < 34816){               // pW1: nb 0..16, kc 0..31 (K=1024)
      int idx = h, lane = idx & 63, kc = (idx >> 6) & 31, nb = idx >> 11;
      int ln = lane & 15, q = lane >> 4;
      #pragma unroll
      for (int j = 0; j < 8; j++){
        int k = kc * 32 + q * 8 + j;
        v8[j] = (nb < 16) ? wfc1[(size_t)k * 256 + nb * 16 + ln]
                          : wskip[(size_t)k * 16 + ln];
      }
      dst = pW1 + (size_t)idx * 8;
    } else if (h < 67584){        // pF1: v, nb 0..15, kc 0..1 (K=64)
      int idx = h - 34816, lane = idx & 63, kc = (idx >> 6) & 1, nb = (idx >> 7) & 15, v = idx >> 11;
      int ln = lane & 15, q = lane >> 4;
      #pragma unroll
      for (int j = 0; j < 8; j++){
        int k = kc * 32 + q * 8 + j;
        v8[j] = vfc1[((size_t)v * 64 + k) * 256 + nb * 16 + ln];
      }
      dst = pF1 + (size_t)idx * 8;
    } else if (h < 100352){       // pSk
      int idx = h - 67584, lane = idx & 63, kc = (idx >> 6) & 1, nb = (idx >> 7) & 15, v = idx >> 11;
      int ln = lane & 15, q = lane >> 4;
      #pragma unroll
      for (int j = 0; j < 8; j++){
        int k = kc * 32 + q * 8 + j;
        v8[j] = vskip[((size_t)v * 64 + k) * 256 + nb * 16 + ln];
      }
      dst = pSk + (size_t)idx * 8;
    } else if (h < 231424){       // pF2: v, nb, kc 0..7 (K=256)
      int idx = h - 100352, lane = idx & 63, kc = (idx >> 6) & 7, nb = (idx >> 9) & 15, v = idx >> 13;
      int ln = lane & 15, q = lane >> 4;
      #pragma unroll
      for (int j = 0; j < 8; j++){
        int k = kc * 32 + q * 8 + j;
        v8[j] = vfc2[((size_t)v * 256 + k) * 256 + nb * 16 + ln];
      }
      dst = pF2 + (size_t)idx * 8;
    } else {                      // pGa
      int idx = h - 231424, lane = idx & 63, kc = (idx >> 6) & 7, nb = (idx >> 9) & 15, v = idx >> 13;
      int ln = lane & 15, q = lane >> 4;
      #pragma unroll
      for (int j = 0; j < 8; j++){
        int k = kc * 32 + q * 8 + j;
        v8[j] = vgate[((size_t)v * 256 + k) * 256 + nb * 16 + ln];
      }
      dst = pGa + (size_t)idx * 8;
    }
  }
  u16x8 t;
  #pragma unroll
  for (int j = 0; j < 8; j++) t[j] = f2b(v8[j]);
  *(uint4*)dst = __builtin_bit_cast(uint4, t);
}

// ---------------------------------------------------------------------------
// Kernel 1: weight GRN -> softmax weights w [N,16] (fp32, in ws).
// 512 blocks x 32 rows, 512 threads = 8 waves.
// Waves 0..6 -> nb {2w,2w+1}; wave 7 -> nb {14,15,16(=skip)}. A-frags from
// pre-packed pX (no cvt). h stored bf16 (LDS 40KB -> 4 blocks/CU capable).
// ---------------------------------------------------------------------------
__global__ __launch_bounds__(512, 4) void k_weight_grn(
    const u16* __restrict__ pX, const u16* __restrict__ pW1,
    const float* __restrict__ b1, const float* __restrict__ W2, const float* __restrict__ b2,
    const float* __restrict__ Wg, const float* __restrict__ bg, const float* __restrict__ bs,
    float* __restrict__ w_out)
{
  __shared__ u16 sH[32 * 264];       // bf16 h
  __shared__ float sR[32 * 16];      // res fp32
  __shared__ float sY[32 * 16];
  __shared__ float sG[32 * 16];
  __shared__ float sW2f[256 * 16];   // fp32 W2
  __shared__ float sWgf[256];        // fp32 Wg

  const int tid  = threadIdx.x;
  const int lane = tid & 63;
  const int wid  = tid >> 6;
  const int ln   = lane & 15;
  const int q    = lane >> 4;
  const int row0 = blockIdx.x * 32;
  const int nb0  = wid * 2;
  const int ncnt = (wid == 7) ? 3 : 2;

  // stage W2 [256][16] fp32 + Wg (before MFMA loop so loads overlap)
  #pragma unroll
  for (int u = 0; u < 2; u++)
    *(float4*)&sW2f[tid * 8 + u * 4] = *(const float4*)&W2[tid * 8 + u * 4];
  if (tid < 256) sWgf[tid] = Wg[tid];

  f32x4 acc[2][3];
  #pragma unroll
  for (int mb = 0; mb < 2; mb++)
    #pragma unroll
    for (int i = 0; i < 3; i++){ acc[mb][i][0]=0.f; acc[mb][i][1]=0.f; acc[mb][i][2]=0.f; acc[mb][i][3]=0.f; }

  for (int kc = 0; kc < 32; kc++){
    bf16x8 a[2];
    #pragma unroll
    for (int mb = 0; mb < 2; mb++)
      a[mb] = ldb(&pX[((size_t)(blockIdx.x * 2 + mb) * 32 + kc) * 512 + lane * 8]);
    #pragma unroll
    for (int i = 0; i < 3; i++){
      if (i < ncnt){
        bf16x8 b = ldb(&pW1[(size_t)((nb0 + i) * 32 + kc) * 512 + lane * 8]);
        #pragma unroll
        for (int mb = 0; mb < 2; mb++) acc[mb][i] = mfma16(a[mb], b, acc[mb][i]);
      }
    }
  }

  // write h (bf16) / res (fp32)
  #pragma unroll
  for (int i = 0; i < 3; i++){
    if (i < ncnt){
      int nb = nb0 + i;
      int col = nb * 16 + ln;
      float vb = (nb < 16) ? b1[col] : bs[ln];
      #pragma unroll
      for (int mb = 0; mb < 2; mb++){
        #pragma unroll
        for (int r = 0; r < 4; r++){
          int lr = mb * 16 + q * 4 + r;
          float v = acc[mb][i][r] + vb;
          if (nb < 16) sH[lr * 264 + col] = f2b(eluf(v));
          else         sR[lr * 16 + ln] = v;
        }
      }
    }
  }
  __syncthreads();

  // y = h @ W2 + b2 : thread r = tid>>4 (0..31), 1 col
  {
    int r = tid >> 4, j = tid & 15;
    float a0 = b2[j];
    #pragma unroll 8
    for (int k = 0; k < 256; k++)
      a0 += b2f(sH[r * 264 + k]) * sW2f[k * 16 + j];
    sY[r * 16 + j] = a0;
  }
  __syncthreads();

  // gate = sigmoid(y @ Wg + bg)
  {
    int r = tid >> 4, j = tid & 15;
    float g0 = bg[j];
    #pragma unroll
    for (int k = 0; k < 16; k++)
      g0 += sY[r * 16 + k] * sWgf[k * 16 + j];
    sG[r * 16 + j] = sigf(g0);
  }
  __syncthreads();

  // softmax over 16
  if (tid < 32){
    int r = tid;
    float l[16]; float m = -1e30f;
    #pragma unroll
    for (int j = 0; j < 16; j++){
      float v = sR[r * 16 + j] + sG[r * 16 + j] * sY[r * 16 + j];
      l[j] = v; m = fmaxf(m, v);
    }
    float s = 0.f;
    #pragma unroll
    for (int j = 0; j < 16; j++){ l[j] = __expf(l[j] - m); s += l[j]; }
    float inv = 1.f / s;
    #pragma unroll
    for (int j = 0; j < 16; j++) w_out[(size_t)(row0 + r) * 16 + j] = l[j] * inv;
  }
}

// ---------------------------------------------------------------------------
// Kernel 2: per-variable GRNs. 512 blocks x 32 rows, all 16 v per block ->
// each out element written exactly once (no atomics, no zeroing, no combine).
// 512 threads = 8 waves; wave wid owns 32-col slice (nb {2w,2w+1}) for all
// 32 rows (mb 0..1). Dual LDS buffers (sHh for hv, sHy for yv) cut barriers
// to 2 per v:  fc1+skip -> B1 -> fc2(read h, write y) -> B2 -> gate(read y).
// B2 protects h vs next-v overwrite; B1 protects y vs next-v fc2 writes.
// LDS ~36KB, 512 thr -> up to 4 blocks/CU for barrier overlap.
// ---------------------------------------------------------------------------
__global__ __launch_bounds__(512, 4) void k_var_grn(
    const u16* __restrict__ pX,
    const u16* __restrict__ pF1, const u16* __restrict__ pSk,
    const u16* __restrict__ pF2, const u16* __restrict__ pGa,
    const float* __restrict__ b1, const float* __restrict__ b2,
    const float* __restrict__ bg, const float* __restrict__ bs,
    const float* __restrict__ w_in, float* __restrict__ out)
{
  __shared__ u16 sHh[32 * 264];      // bf16 hv
  __shared__ u16 sHy[32 * 264];      // bf16 yv
  __shared__ float sWt[32 * 16];     // softmax weights fp32

  const int tid  = threadIdx.x;
  const int lane = tid & 63;
  const int wid  = tid >> 6;
  const int ln   = lane & 15;
  const int q    = lane >> 4;
  const int row0 = blockIdx.x * 32;
  const int rb0  = blockIdx.x * 2;
  const int nb0  = wid * 2;

  sWt[tid] = w_in[(size_t)row0 * 16 + tid];
  __syncthreads();

  f32x4 z[2][2];
  #pragma unroll
  for (int mb = 0; mb < 2; mb++)
    #pragma unroll
    for (int i = 0; i < 2; i++){ z[mb][i][0]=0.f; z[mb][i][1]=0.f; z[mb][i][2]=0.f; z[mb][i][3]=0.f; }

  #pragma unroll 1
  for (int v = 0; v < 16; v++){
    // A-fragments from pre-packed pX, kcg = v*2 + ks
    bf16x8 a0[2], a1[2];
    #pragma unroll
    for (int mb = 0; mb < 2; mb++){
      const u16* xp = &pX[((size_t)(rb0 + mb) * 32 + v * 2) * 512 + lane * 8];
      a0[mb] = ldb(xp);
      a1[mb] = ldb(xp + 512);
    }
    float wv[2][4];
    #pragma unroll
    for (int mb = 0; mb < 2; mb++)
      #pragma unroll
      for (int r = 0; r < 4; r++) wv[mb][r] = sWt[(mb * 16 + q * 4 + r) * 16 + v];

    // ---- phase 1a: hv = elu(Xv @ W1v + b1) -> sHh
    f32x4 hacc[2][2];
    #pragma unroll
    for (int mb = 0; mb < 2; mb++)
      #pragma unroll
      for (int i = 0; i < 2; i++){ hacc[mb][i][0]=0.f; hacc[mb][i][1]=0.f; hacc[mb][i][2]=0.f; hacc[mb][i][3]=0.f; }
    #pragma unroll
    for (int ks = 0; ks < 2; ks++){
      bf16x8 B0 = ldb(&pF1[(size_t)((v * 16 + nb0) * 2 + ks) * 512 + lane * 8]);
      bf16x8 B1 = ldb(&pF1[(size_t)((v * 16 + nb0 + 1) * 2 + ks) * 512 + lane * 8]);
      #pragma unroll
      for (int mb = 0; mb < 2; mb++){
        bf16x8 a = ks ? a1[mb] : a0[mb];
        hacc[mb][0] = mfma16(a, B0, hacc[mb][0]);
        hacc[mb][1] = mfma16(a, B1, hacc[mb][1]);
      }
    }
    #pragma unroll
    for (int i = 0; i < 2; i++){
      int col = (nb0 + i) * 16 + ln;
      float vb = b1[v * 256 + col];
      #pragma unroll
      for (int mb = 0; mb < 2; mb++)
        #pragma unroll
        for (int r = 0; r < 4; r++)
          sHh[(mb * 16 + q * 4 + r) * 264 + col] = f2b(eluf(hacc[mb][i][r] + vb));
    }

    // ---- phase 1b: rv = Xv @ Wsv + bs ; z += wv * rv  (no LDS dependency)
    f32x4 racc[2][2];
    #pragma unroll
    for (int mb = 0; mb < 2; mb++)
      #pragma unroll
      for (int i = 0; i < 2; i++){ racc[mb][i][0]=0.f; racc[mb][i][1]=0.f; racc[mb][i][2]=0.f; racc[mb][i][3]=0.f; }
    #pragma unroll
    for (int ks = 0; ks < 2; ks++){
      bf16x8 B0 = ldb(&pSk[(size_t)((v * 16 + nb0) * 2 + ks) * 512 + lane * 8]);
      bf16x8 B1 = ldb(&pSk[(size_t)((v * 16 + nb0 + 1) * 2 + ks) * 512 + lane * 8]);
      #pragma unroll
      for (int mb = 0; mb < 2; mb++){
        bf16x8 a = ks ? a1[mb] : a0[mb];
        racc[mb][0] = mfma16(a, B0, racc[mb][0]);
        racc[mb][1] = mfma16(a, B1, racc[mb][1]);
      }
    }
    #pragma unroll
    for (int i = 0; i < 2; i++){
      float vb = bs[v * 256 + (nb0 + i) * 16 + ln];
      #pragma unroll
      for (int mb = 0; mb < 2; mb++)
        #pragma unroll
        for (int r = 0; r < 4; r++) z[mb][i][r] += wv[mb][r] * (racc[mb][i][r] + vb);
    }
    __syncthreads();   // B1: hv visible; prev-v yv reads done before sHy rewrite

    // ---- phase 2: yv = hv @ W2v + b2  (read sHh, write sHy)
    f32x4 yacc[2][2];
    #pragma unroll
    for (int mb = 0; mb < 2; mb++)
      #pragma unroll
      for (int i = 0; i < 2; i++){ yacc[mb][i][0]=0.f; yacc[mb][i][1]=0.f; yacc[mb][i][2]=0.f; yacc[mb][i][3]=0.f; }
    #pragma unroll
    for (int kc = 0; kc < 8; kc++){
      bf16x8 B0 = ldb(&pF2[(size_t)((v * 16 + nb0) * 8 + kc) * 512 + lane * 8]);
      bf16x8 B1 = ldb(&pF2[(size_t)((v * 16 + nb0 + 1) * 8 + kc) * 512 + lane * 8]);
      #pragma unroll
      for (int mb = 0; mb < 2; mb++){
        bf16x8 ah = *(const bf16x8*)&sHh[(mb * 16 + ln) * 264 + kc * 32 + q * 8];
        yacc[mb][0] = mfma16(ah, B0, yacc[mb][0]);
        yacc[mb][1] = mfma16(ah, B1, yacc[mb][1]);
      }
    }
    f32x4 ysave[2][2];
    #pragma unroll
    for (int i = 0; i < 2; i++){
      int col = (nb0 + i) * 16 + ln;
      float vb = b2[v * 256 + col];
      #pragma unroll
      for (int mb = 0; mb < 2; mb++)
        #pragma unroll
        for (int r = 0; r < 4; r++){
          float yy = yacc[mb][i][r] + vb;
          ysave[mb][i][r] = yy;
          sHy[(mb * 16 + q * 4 + r) * 264 + col] = f2b(yy);
        }
    }
    __syncthreads();   // B2: yv visible; all hv reads done before next-v rewrite

    // ---- phase 3: gv = sigmoid(yv @ Wgv + bg); z += wv * gv * yv
    f32x4 gacc[2][2];
    #pragma unroll
    for (int mb = 0; mb < 2; mb++)
      #pragma unroll
      for (int i = 0; i < 2; i++){ gacc[mb][i][0]=0.f; gacc[mb][i][1]=0.f; gacc[mb][i][2]=0.f; gacc[mb][i][3]=0.f; }
    #pragma unroll
    for (int kc = 0; kc < 8; kc++){
      bf16x8 B0 = ldb(&pGa[(size_t)((v * 16 + nb0) * 8 + kc) * 512 + lane * 8]);
      bf16x8 B1 = ldb(&pGa[(size_t)((v * 16 + nb0 + 1) * 8 + kc) * 512 + lane * 8]);
      #pragma unroll
      for (int mb = 0; mb < 2; mb++){
        bf16x8 ah = *(const bf16x8*)&sHy[(mb * 16 + ln) * 264 + kc * 32 + q * 8];
        gacc[mb][0] = mfma16(ah, B0, gacc[mb][0]);
        gacc[mb][1] = mfma16(ah, B1, gacc[mb][1]);
      }
    }
    #pragma unroll
    for (int i = 0; i < 2; i++){
      float vb = bg[v * 256 + (nb0 + i) * 16 + ln];
      #pragma unroll
      for (int mb = 0; mb < 2; mb++)
        #pragma unroll
        for (int r = 0; r < 4; r++)
          z[mb][i][r] += wv[mb][r] * sigf(gacc[mb][i][r] + vb) * ysave[mb][i][r];
    }
    // next v's sHh writes are after B2; next v's sHy writes after next B1. safe.
  }

  // store z -> out (fp32), single writer per element
  #pragma unroll
  for (int i = 0; i < 2; i++){
    int col = (nb0 + i) * 16 + ln;
    #pragma unroll
    for (int mb = 0; mb < 2; mb++)
      #pragma unroll
      for (int r = 0; r < 4; r++)
        out[(size_t)(row0 + mb * 16 + q * 4 + r) * 256 + col] = z[mb][i][r];
  }
}

// ---------------------------------------------------------------------------
extern "C" void kernel_launch(void* const* d_in, const int* in_sizes, int n_in,
                              void* d_out, int out_size, void* d_ws, size_t ws_size,
                              hipStream_t stream)
{
  const float* x     = (const float*)d_in[0];
  const float* wfc1w = (const float*)d_in[1];
  const float* wfc1b = (const float*)d_in[2];
  const float* wfc2w = (const float*)d_in[3];
  const float* wfc2b = (const float*)d_in[4];
  const float* wgw   = (const float*)d_in[5];
  const float* wgb   = (const float*)d_in[6];
  const float* wsw   = (const float*)d_in[7];
  const float* wsb   = (const float*)d_in[8];
  const float* vfc1w = (const float*)d_in[9];
  const float* vfc1b = (const float*)d_in[10];
  const float* vfc2w = (const float*)d_in[11];
  const float* vfc2b = (const float*)d_in[12];
  const float* vgw   = (const float*)d_in[13];
  const float* vgb   = (const float*)d_in[14];
  const float* vsw   = (const float*)d_in[15];
  const float* vsb   = (const float*)d_in[16];

  u16* ws   = (u16*)d_ws;
  u16* pX   = ws;                      // 16777216 u16 (32 MB)
  u16* pW1  = pX + 16777216;           // 278528 u16
  u16* pF1  = pW1 + 278528;            // 262144
  u16* pSk  = pF1 + 262144;            // 262144
  u16* pF2  = pSk + 262144;            // 1048576
  u16* pGa  = pF2 + 1048576;           // 1048576
  float* w_ws = (float*)(pGa + 1048576); // 16384*16 fp32

  k_pack<<<dim3(9608), dim3(256), 0, stream>>>(
      x, wfc1w, wsw, vfc1w, vfc2w, vgw, vsw, pX, pW1, pF1, pSk, pF2, pGa);

  k_weight_grn<<<dim3(512), dim3(512), 0, stream>>>(
      pX, pW1, wfc1b, wfc2w, wfc2b, wgw, wgb, wsb, w_ws);

  k_var_grn<<<dim3(512), dim3(512), 0, stream>>>(
      pX, pF1, pSk, pF2, pGa, vfc1b, vfc2b, vgb, vsb, w_ws, (float*)d_out);
}